// Round 3
// baseline (1208.177 us; speedup 1.0000x reference)
//
#include <hip/hip_runtime.h>
#include <cstdint>
#include <cstddef>

#define DIMD 1024
#define HIDD 1536
#define SSEQ 4096
#define NBATCH 4
#define NCHK 32                     // scan chunks per sequence
#define CSZ  (SSEQ/NCHK)            // 128 steps per chunk

typedef float  f32x4 __attribute__((ext_vector_type(4)));
typedef short  s16x8 __attribute__((ext_vector_type(8)));
typedef float  fx4   __attribute__((ext_vector_type(4)));
typedef unsigned short u16x4 __attribute__((ext_vector_type(4)));

__device__ __forceinline__ unsigned short f2bf(float f) {
  union { float f; unsigned u; } v; v.f = f;
  unsigned r = v.u + 0x7fffu + ((v.u >> 16) & 1u);   // RNE
  return (unsigned short)(r >> 16);
}
__device__ __forceinline__ float bf2f(unsigned short u) {
  union { unsigned u; float f; } v; v.u = (unsigned)u << 16;
  return v.f;
}
__device__ __forceinline__ float gelu_f(float x) {
  return 0.5f * x * (1.0f + erff(x * 0.70710678118654752440f));
}
__device__ __forceinline__ float sigmoid_f(float x) {
  return 1.0f / (1.0f + __expf(-x));
}

__device__ __forceinline__ void gload_lds16(const unsigned short* g, unsigned short* l) {
  // async global->LDS, 16B/lane; LDS dest is wave-uniform base + lane*16
  __builtin_amdgcn_global_load_lds((const __attribute__((address_space(1))) void*)g,
                                   (__attribute__((address_space(3))) void*)l, 16, 0, 0);
}

// ---------------- f32 -> bf16 weight pack ----------------
__global__ __launch_bounds__(256) void cvt_k(const float* __restrict__ in,
                                             unsigned short* __restrict__ out, int n4) {
  int i = blockIdx.x * 256 + threadIdx.x;
  if (i >= n4) return;
  fx4 v = *(const fx4*)&in[(size_t)i * 4];
  u16x4 o; o[0] = f2bf(v[0]); o[1] = f2bf(v[1]); o[2] = f2bf(v[2]); o[3] = f2bf(v[3]);
  *(u16x4*)&out[(size_t)i * 4] = o;
}

// ---------------- RMSNorm: f32 in -> bf16 out (one row per block) ----------------
__global__ __launch_bounds__(256) void rms_k(const float* __restrict__ x,
                                             const float* __restrict__ w,
                                             unsigned short* __restrict__ o) {
  const int row = blockIdx.x, tid = threadIdx.x;
  fx4 v = *(const fx4*)&x[(size_t)row * DIMD + tid * 4];
  float s = v[0]*v[0] + v[1]*v[1] + v[2]*v[2] + v[3]*v[3];
  #pragma unroll
  for (int off = 32; off > 0; off >>= 1) s += __shfl_xor(s, off);
  __shared__ float ws4[4];
  if ((tid & 63) == 0) ws4[tid >> 6] = s;
  __syncthreads();
  s = ws4[0] + ws4[1] + ws4[2] + ws4[3];
  const float r = rsqrtf(s * (1.0f / DIMD) + 1e-5f);
  fx4 wv = *(const fx4*)&w[tid * 4];
  u16x4 ob;
  ob[0] = f2bf(v[0] * r * wv[0]); ob[1] = f2bf(v[1] * r * wv[1]);
  ob[2] = f2bf(v[2] * r * wv[2]); ob[3] = f2bf(v[3] * r * wv[3]);
  *(u16x4*)&o[(size_t)row * DIMD + tid * 4] = ob;
}

// ---------------- depthwise causal conv1d K=4 (bf16 in, bf16 out) ----------------
__global__ __launch_bounds__(256) void conv_k(const unsigned short* __restrict__ u,
                                              const float* __restrict__ cw,
                                              const float* __restrict__ cb,
                                              unsigned short* __restrict__ uc) {
  const int i4 = blockIdx.x * 256 + threadIdx.x;        // over Mg*HIDD/4 (grid exact)
  const int hb4 = i4 % (HIDD / 4);
  const int s = (i4 / (HIDD / 4)) % SSEQ;
  const size_t e0 = (size_t)i4 * 4;
  u16x4 u0 = *(const u16x4*)&u[e0];
  u16x4 u1 = {0,0,0,0}, u2 = {0,0,0,0}, u3 = {0,0,0,0};
  if (s >= 1) u1 = *(const u16x4*)&u[e0 - HIDD];
  if (s >= 2) u2 = *(const u16x4*)&u[e0 - 2 * HIDD];
  if (s >= 3) u3 = *(const u16x4*)&u[e0 - 3 * HIDD];
  u16x4 ob;
  #pragma unroll
  for (int e = 0; e < 4; ++e) {
    const int h = hb4 * 4 + e;
    fx4 w = *(const fx4*)&cw[h * 4];   // w[3] = current-sample tap
    float r = cb[h] + bf2f(u0[e])*w[3] + bf2f(u1[e])*w[2] + bf2f(u2[e])*w[1] + bf2f(u3[e])*w[0];
    ob[e] = f2bf(r);
  }
  *(u16x4*)&uc[e0] = ob;
}

// ---------------- GEMM: C[M,N] = A[M,K] * W[N,K]^T (bf16 in, f32 acc) ----------------
// m97 structure: 128x128 tile, 4 waves (2x2) of 4x4 16x16x32 MFMA, global_load_lds w=16
// EPI: 1 = store bf16(acc); 2 = f32 store auxf+acc; 3 = bf16 store gelu(auxb)*acc
template <int EPI>
__global__ __launch_bounds__(256, 2) void gemm_bt(
    const unsigned short* __restrict__ A, const unsigned short* __restrict__ Bw,
    float* __restrict__ Cf, unsigned short* __restrict__ Cb,
    const float* __restrict__ auxf, const unsigned short* __restrict__ auxb,
    int M, int N, int K) {
  __shared__ unsigned short sA[128 * 32];
  __shared__ unsigned short sB[128 * 32];
  const int tid = threadIdx.x;
  const int lane = tid & 63;
  const int wave = tid >> 6;
  const int wr = wave >> 1, wc = wave & 1;
  const int bn = blockIdx.x, bm = blockIdx.y;
  const unsigned short* Ab = A + (size_t)(bm * 128) * K;
  const unsigned short* Bb = Bw + (size_t)(bn * 128) * K;
  const int r0 = tid >> 2;            // staging row 0..63
  const int cbk = (tid & 3) * 8;      // staging k-col (8 shorts = 16B)
  const int fr = lane & 15;
  const int kg = (lane >> 4) * 8;
  f32x4 acc[4][4] = {};
  for (int k0 = 0; k0 < K; k0 += 32) {
    gload_lds16(Ab + (size_t)r0 * K + k0 + cbk,        &sA[wave * 512]);
    gload_lds16(Ab + (size_t)(r0 + 64) * K + k0 + cbk, &sA[2048 + wave * 512]);
    gload_lds16(Bb + (size_t)r0 * K + k0 + cbk,        &sB[wave * 512]);
    gload_lds16(Bb + (size_t)(r0 + 64) * K + k0 + cbk, &sB[2048 + wave * 512]);
    __syncthreads();
    s16x8 af[4], bf[4];
    #pragma unroll
    for (int m = 0; m < 4; ++m) af[m] = *(const s16x8*)&sA[(wr * 64 + m * 16 + fr) * 32 + kg];
    #pragma unroll
    for (int n = 0; n < 4; ++n) bf[n] = *(const s16x8*)&sB[(wc * 64 + n * 16 + fr) * 32 + kg];
    #pragma unroll
    for (int m = 0; m < 4; ++m)
      #pragma unroll
      for (int n = 0; n < 4; ++n)
        acc[m][n] = __builtin_amdgcn_mfma_f32_16x16x32_bf16(af[m], bf[n], acc[m][n], 0, 0, 0);
    __syncthreads();
  }
  const int rbase = bm * 128 + wr * 64;
  const int cbase = bn * 128 + wc * 64;
  #pragma unroll
  for (int m = 0; m < 4; ++m) {
    #pragma unroll
    for (int n = 0; n < 4; ++n) {
      const int col = cbase + n * 16 + fr;
      #pragma unroll
      for (int j = 0; j < 4; ++j) {
        const int row = rbase + m * 16 + (lane >> 4) * 4 + j;
        const size_t idx = (size_t)row * N + col;
        float v = acc[m][n][j];
        if constexpr (EPI == 1) {
          Cb[idx] = f2bf(v);
        } else if constexpr (EPI == 2) {
          Cf[idx] = auxf[idx] + v;
        } else {
          Cb[idx] = f2bf(gelu_f(bf2f(auxb[idx])) * v);
        }
      }
    }
  }
}

// ---------------- RG-LRU chunked scan (bf16 inputs) ----------------
__global__ __launch_bounds__(256) void scan1_k(
    const unsigned short* __restrict__ ig, const unsigned short* __restrict__ rg,
    const unsigned short* __restrict__ uc,
    const float* __restrict__ inb, const float* __restrict__ gb, const float* __restrict__ lam,
    float* __restrict__ cA, float* __restrict__ cB) {
  const int h = blockIdx.y * 256 + threadIdx.x;
  const int b = blockIdx.x / NCHK, c = blockIdx.x % NCHK;   // b is group-local
  const float sl = -8.0f * log1pf(__expf(lam[h]));
  const float bi = inb[h], bg = gb[h];
  size_t idx = ((size_t)b * SSEQ + (size_t)c * CSZ) * HIDD + h;
  float A = 1.0f, Bv = 0.0f;
  for (int s = 0; s < CSZ; ++s, idx += HIDD) {
    float a = __expf(sl * sigmoid_f(bf2f(rg[idx]) + bg));
    float beta = sqrtf(1.0f - a * a + 1e-6f);
    float xb = beta * sigmoid_f(bf2f(ig[idx]) + bi) * bf2f(uc[idx]);
    A *= a; Bv = a * Bv + xb;
  }
  const size_t o = ((size_t)b * NCHK + c) * HIDD + h;
  cA[o] = A; cB[o] = Bv;
}

__global__ __launch_bounds__(256) void scan2_k(const float* __restrict__ cA,
                                               const float* __restrict__ cB,
                                               float* __restrict__ carry) {
  const int i = blockIdx.x * 256 + threadIdx.x;   // over g*HIDD
  const int b = i / HIDD, h = i % HIDD;
  float run = 0.0f;
  for (int c = 0; c < NCHK; ++c) {
    const size_t idx = ((size_t)b * NCHK + c) * HIDD + h;
    carry[idx] = run;
    run = cA[idx] * run + cB[idx];
  }
}

__global__ __launch_bounds__(256) void scan3_k(
    const unsigned short* __restrict__ ig, const unsigned short* __restrict__ rg,
    const unsigned short* __restrict__ uc,
    const float* __restrict__ inb, const float* __restrict__ gb, const float* __restrict__ lam,
    const float* __restrict__ carry, const unsigned short* __restrict__ gate,
    unsigned short* __restrict__ gated) {
  const int h = blockIdx.y * 256 + threadIdx.x;
  const int b = blockIdx.x / NCHK, c = blockIdx.x % NCHK;
  const float sl = -8.0f * log1pf(__expf(lam[h]));
  const float bi = inb[h], bg = gb[h];
  float hh = carry[((size_t)b * NCHK + c) * HIDD + h];
  size_t idx = ((size_t)b * SSEQ + (size_t)c * CSZ) * HIDD + h;
  for (int s = 0; s < CSZ; ++s, idx += HIDD) {
    float a = __expf(sl * sigmoid_f(bf2f(rg[idx]) + bg));
    float beta = sqrtf(1.0f - a * a + 1e-6f);
    float xb = beta * sigmoid_f(bf2f(ig[idx]) + bi) * bf2f(uc[idx]);
    hh = a * hh + xb;
    gated[idx] = f2bf(gelu_f(bf2f(gate[idx])) * hh);
  }
}

extern "C" void kernel_launch(void* const* d_in, const int* in_sizes, int n_in,
                              void* d_out, int out_size, void* d_ws, size_t ws_size,
                              hipStream_t stream) {
  const float* x          = (const float*)d_in[0];
  const float* W_in       = (const float*)d_in[1];
  const float* W_gate     = (const float*)d_in[2];
  const float* conv_w     = (const float*)d_in[3];
  const float* conv_b     = (const float*)d_in[4];
  const float* W_out      = (const float*)d_in[5];
  const float* rg_in_w    = (const float*)d_in[6];
  const float* rg_in_b    = (const float*)d_in[7];
  const float* rg_gate_w  = (const float*)d_in[8];
  const float* rg_gate_b  = (const float*)d_in[9];
  const float* lam        = (const float*)d_in[10];
  const float* mlp_gate_w = (const float*)d_in[11];
  const float* mlp_up_w   = (const float*)d_in[12];
  const float* mlp_down_w = (const float*)d_in[13];
  const float* n1w        = (const float*)d_in[14];
  const float* n2w        = (const float*)d_in[15];
  float* out = (float*)d_out;

  // ---- workspace-size-adaptive batch grouping (deterministic in ws_size) ----
  const size_t WB = ((size_t)6 * HIDD * DIMD + (size_t)2 * HIDD * HIDD) * 2;  // bf16 weights ~28.3MB
  auto need = [&](int g) -> size_t {
    const size_t Mg = (size_t)g * SSEQ;
    size_t a = Mg * DIMD * 2                // hbf
             + 5 * Mg * HIDD * 2            // u,gate,uc,ig,rg (bf16)
             + Mg * DIMD * 4                // x2 (f32)
             + 3 * (size_t)g * NCHK * HIDD * 4;  // cA,cBv,carry
    return WB + a + (size_t)(1 << 20);      // 1MB slack for 256B padding
  };
  int g = 1;
  if (ws_size >= need(4)) g = 4;
  else if (ws_size >= need(2)) g = 2;
  const int Mg = g * SSEQ;

  char* base = (char*)d_ws;
  size_t off = 0;
  auto alloc = [&](size_t bytes) -> void* {
    void* p = base + off;
    off += (bytes + 255) & ~(size_t)255;
    return p;
  };

  // bf16 weight copies
  unsigned short* wb_in    = (unsigned short*)alloc((size_t)HIDD * DIMD * 2);
  unsigned short* wb_gate  = (unsigned short*)alloc((size_t)HIDD * DIMD * 2);
  unsigned short* wb_rgin  = (unsigned short*)alloc((size_t)HIDD * HIDD * 2);
  unsigned short* wb_rggt  = (unsigned short*)alloc((size_t)HIDD * HIDD * 2);
  unsigned short* wb_out   = (unsigned short*)alloc((size_t)DIMD * HIDD * 2);
  unsigned short* wb_mgate = (unsigned short*)alloc((size_t)HIDD * DIMD * 2);
  unsigned short* wb_mup   = (unsigned short*)alloc((size_t)HIDD * DIMD * 2);
  unsigned short* wb_mdown = (unsigned short*)alloc((size_t)DIMD * HIDD * 2);
  // per-group activations (bf16 except x2)
  unsigned short* hbf    = (unsigned short*)alloc((size_t)Mg * DIMD * 2);  // also n2
  unsigned short* u_b    = (unsigned short*)alloc((size_t)Mg * HIDD * 2);  // also gated
  unsigned short* gate_b = (unsigned short*)alloc((size_t)Mg * HIDD * 2);
  unsigned short* uc_b   = (unsigned short*)alloc((size_t)Mg * HIDD * 2);  // also gaux
  unsigned short* ig_b   = (unsigned short*)alloc((size_t)Mg * HIDD * 2);  // also min_b
  unsigned short* rg_b   = (unsigned short*)alloc((size_t)Mg * HIDD * 2);
  float*          x2     = (float*)alloc((size_t)Mg * DIMD * 4);
  float* cA    = (float*)alloc((size_t)g * NCHK * HIDD * 4);
  float* cBv   = (float*)alloc((size_t)g * NCHK * HIDD * 4);
  float* carry = (float*)alloc((size_t)g * NCHK * HIDD * 4);
  unsigned short* gated = u_b;    // u dead after conv
  unsigned short* n2bf  = hbf;    // h dead after gate GEMM
  unsigned short* gaux  = uc_b;   // uc dead after scan3
  unsigned short* min_b = ig_b;   // ig dead after scan3

  const int T = 256;
  // pack weights to bf16 (once per call)
  cvt_k<<<HIDD * DIMD / 1024, T, 0, stream>>>(W_in, wb_in, HIDD * DIMD / 4);
  cvt_k<<<HIDD * DIMD / 1024, T, 0, stream>>>(W_gate, wb_gate, HIDD * DIMD / 4);
  cvt_k<<<HIDD * HIDD / 1024, T, 0, stream>>>(rg_in_w, wb_rgin, HIDD * HIDD / 4);
  cvt_k<<<HIDD * HIDD / 1024, T, 0, stream>>>(rg_gate_w, wb_rggt, HIDD * HIDD / 4);
  cvt_k<<<DIMD * HIDD / 1024, T, 0, stream>>>(W_out, wb_out, DIMD * HIDD / 4);
  cvt_k<<<HIDD * DIMD / 1024, T, 0, stream>>>(mlp_gate_w, wb_mgate, HIDD * DIMD / 4);
  cvt_k<<<HIDD * DIMD / 1024, T, 0, stream>>>(mlp_up_w, wb_mup, HIDD * DIMD / 4);
  cvt_k<<<DIMD * HIDD / 1024, T, 0, stream>>>(mlp_down_w, wb_mdown, DIMD * HIDD / 4);

  for (int b0 = 0; b0 < NBATCH; b0 += g) {
    const float* x_g  = x   + (size_t)b0 * SSEQ * DIMD;
    float*      out_g = out + (size_t)b0 * SSEQ * DIMD;
    // mixer branch
    rms_k<<<Mg, T, 0, stream>>>(x_g, n1w, hbf);
    gemm_bt<1><<<dim3(HIDD / 128, Mg / 128), T, 0, stream>>>(hbf, wb_in, nullptr, u_b, nullptr, nullptr, Mg, HIDD, DIMD);
    gemm_bt<1><<<dim3(HIDD / 128, Mg / 128), T, 0, stream>>>(hbf, wb_gate, nullptr, gate_b, nullptr, nullptr, Mg, HIDD, DIMD);
    conv_k<<<Mg * (HIDD / 4) / T, T, 0, stream>>>(u_b, conv_w, conv_b, uc_b);
    gemm_bt<1><<<dim3(HIDD / 128, Mg / 128), T, 0, stream>>>(uc_b, wb_rgin, nullptr, ig_b, nullptr, nullptr, Mg, HIDD, HIDD);
    gemm_bt<1><<<dim3(HIDD / 128, Mg / 128), T, 0, stream>>>(uc_b, wb_rggt, nullptr, rg_b, nullptr, nullptr, Mg, HIDD, HIDD);
    scan1_k<<<dim3(g * NCHK, HIDD / 256), T, 0, stream>>>(ig_b, rg_b, uc_b, rg_in_b, rg_gate_b, lam, cA, cBv);
    scan2_k<<<g * HIDD / 256, T, 0, stream>>>(cA, cBv, carry);
    scan3_k<<<dim3(g * NCHK, HIDD / 256), T, 0, stream>>>(ig_b, rg_b, uc_b, rg_in_b, rg_gate_b, lam, carry, gate_b, gated);
    gemm_bt<2><<<dim3(DIMD / 128, Mg / 128), T, 0, stream>>>(gated, wb_out, x2, nullptr, x_g, nullptr, Mg, DIMD, HIDD);
    // GEGLU MLP branch
    rms_k<<<Mg, T, 0, stream>>>(x2, n2w, n2bf);
    gemm_bt<1><<<dim3(HIDD / 128, Mg / 128), T, 0, stream>>>(n2bf, wb_mgate, nullptr, gaux, nullptr, nullptr, Mg, HIDD, DIMD);
    gemm_bt<3><<<dim3(HIDD / 128, Mg / 128), T, 0, stream>>>(n2bf, wb_mup, nullptr, min_b, nullptr, gaux, Mg, HIDD, DIMD);
    gemm_bt<2><<<dim3(DIMD / 128, Mg / 128), T, 0, stream>>>(min_b, wb_mdown, out_g, nullptr, x2, nullptr, Mg, DIMD, HIDD);
  }
}